// Round 5
// baseline (317.925 us; speedup 1.0000x reference)
//
#include <hip/hip_runtime.h>
#include <hip/hip_bf16.h>

typedef unsigned int u32;
typedef __attribute__((ext_vector_type(8))) short bf16x8;
typedef __attribute__((ext_vector_type(4))) float f32x4;

#define N_NODES 2048
#define INF __builtin_inff()
#define SCAP 88   // survivor buffer per node

__device__ __forceinline__ float bflo(u32 u){ return __uint_as_float(u << 16); }
__device__ __forceinline__ float bfhi(u32 u){ return __uint_as_float(u & 0xFFFF0000u); }
__device__ __forceinline__ u32 packbf(float a, float b){
  u32 ua = __float_as_uint(a), ub = __float_as_uint(b);
  u32 ra = (ua + 0x7FFFu + ((ua >> 16) & 1u)) >> 16;
  u32 rb = (ub + 0x7FFFu + ((ub >> 16) & 1u)) >> 16;
  return ra | (rb << 16);
}

// branchless insert of v into sorted-ascending 16-list (distances only)
__device__ __forceinline__ void ins16(float (&ad)[16], float v) {
#pragma unroll
  for (int t = 15; t >= 1; --t)
    ad[t] = __builtin_amdgcn_fmed3f(v, ad[t-1], ad[t]);
  ad[0] = fminf(ad[0], v);
}

__device__ __forceinline__ float dist2(float cx, float cy, float cz,
                                       float jx, float jy, float jz) {
  float dx = cx - jx, dy = cy - jy, dz = cz - jz;
  return fmaf(dz, dz, fmaf(dy, dy, dx * dx));
}

// merge 4 sorted-ascending 16-lists held by the 4 sublanes (tid^1 then tid^2)
// into the 16-smallest multiset (result may be unsorted bitonic).
__device__ __forceinline__ void merge4(float (&ad)[16], int tid) {
  float bd[16];
#pragma unroll
  for (int q = 0; q < 16; ++q) bd[q] = __shfl(ad[q], tid ^ 1);
#pragma unroll
  for (int q = 0; q < 16; ++q) ad[q] = fminf(ad[q], bd[15 - q]);
#define CED(I, J) { float lo_ = fminf(ad[I], ad[J]); ad[J] = fmaxf(ad[I], ad[J]); ad[I] = lo_; }
  CED(0,8) CED(1,9) CED(2,10) CED(3,11) CED(4,12) CED(5,13) CED(6,14) CED(7,15)
  CED(0,4) CED(1,5) CED(2,6)  CED(3,7)  CED(8,12) CED(9,13) CED(10,14) CED(11,15)
  CED(0,2) CED(1,3) CED(4,6)  CED(5,7)  CED(8,10) CED(9,11) CED(12,14) CED(13,15)
  CED(0,1) CED(2,3) CED(4,5)  CED(6,7)  CED(8,9)  CED(10,11) CED(12,13) CED(14,15)
#undef CED
#pragma unroll
  for (int q = 0; q < 16; ++q) bd[q] = __shfl(ad[q], tid ^ 2);
#pragma unroll
  for (int q = 0; q < 16; ++q) ad[q] = fminf(ad[q], bd[15 - q]);
}

__device__ __forceinline__ float max16(const float (&ad)[16]) {
  float t = ad[0];
#pragma unroll
  for (int q = 1; q < 16; ++q) t = fmaxf(t, ad[q]);
  return t;
}

// ---------------------------------------------------------------------------
// K1: exact KNN (K=16, self-excluded) + GCN layer 1 (3->64) fused.
// 1024 blocks x 256 thr; block = 64 nodes of one sample; 4 lanes/node.
// Phase 0: med3 top-16 over quarter-subset j<512 -> tau_hat (upper bound).
// Phase 1: full scan, filter d <= tau_hat -> survivor idx buffer (cap 88).
// Phase 2: exact med3 top-16 over survivors -> tau -> index filter.
// Overflow (prob ~1e-7/node): wave-uniform exact full rescan fallback.
// ---------------------------------------------------------------------------
__global__ __launch_bounds__(256) void k1_knn_l1(
    const float* __restrict__ coords, const float* __restrict__ W1,
    const float* __restrict__ b1, int* __restrict__ nbr, u32* __restrict__ x1)
{
  __shared__ float xs[N_NODES], ys[N_NODES], zs[N_NODES];  // 24 KB SoA
  __shared__ u32   sbuf[64][SCAP];                         // 22 KB survivors
  __shared__ u32   nbuf[64][16];                           //  4 KB final idx
  __shared__ u32   scnt[64], ncnt[64];
  __shared__ float w1s[192];
  __shared__ float b1s[64];
  const int tid   = threadIdx.x;
  const int s     = blockIdx.x >> 5;
  const int chunk = blockIdx.x & 31;
  const float* cs = coords + (size_t)s * (N_NODES * 3);
  for (int k = tid; k < N_NODES; k += 256) {
    xs[k] = cs[3*k]; ys[k] = cs[3*k+1]; zs[k] = cs[3*k+2];
  }
  if (tid < 192) w1s[tid] = W1[tid];
  if (tid < 64)  { b1s[tid] = b1[tid]; scnt[tid] = 0; ncnt[tid] = 0; }
  __syncthreads();

  const int node = (chunk << 6) + (tid >> 2);
  const int sub  = tid & 3;
  const int ln   = tid >> 2;
  const float cx = xs[node], cy = ys[node], cz = zs[node];

  const float4* xs4 = (const float4*)xs;
  const float4* ys4 = (const float4*)ys;
  const float4* zs4 = (const float4*)zs;

  // ---- phase 0: med3 top-16 over j in [0,512) ----
  float ad[16];
#pragma unroll
  for (int q = 0; q < 16; ++q) ad[q] = INF;
  for (int it = 0; it < 32; ++it) {
    const int v4 = (it << 2) + sub;
    float4 xv = xs4[v4], yv = ys4[v4], zv = zs4[v4];
    const int base = v4 << 2;
    float d0 = (base + 0 == node) ? INF : dist2(cx, cy, cz, xv.x, yv.x, zv.x);
    float d1 = (base + 1 == node) ? INF : dist2(cx, cy, cz, xv.y, yv.y, zv.y);
    float d2 = (base + 2 == node) ? INF : dist2(cx, cy, cz, xv.z, yv.z, zv.z);
    float d3 = (base + 3 == node) ? INF : dist2(cx, cy, cz, xv.w, yv.w, zv.w);
    ins16(ad, d0); ins16(ad, d1); ins16(ad, d2); ins16(ad, d3);
  }
  merge4(ad, tid);
  const float tauh = max16(ad);   // upper bound on true d16

  // ---- phase 1: full scan, collect survivors d <= tauh ----
  for (int it = 0; it < 128; ++it) {
    const int v4 = (it << 2) + sub;
    float4 xv = xs4[v4], yv = ys4[v4], zv = zs4[v4];
    const int base = v4 << 2;
    float d0 = dist2(cx, cy, cz, xv.x, yv.x, zv.x);
    float d1 = dist2(cx, cy, cz, xv.y, yv.y, zv.y);
    float d2 = dist2(cx, cy, cz, xv.z, yv.z, zv.z);
    float d3 = dist2(cx, cy, cz, xv.w, yv.w, zv.w);
    if (d0 <= tauh && base + 0 != node) { u32 p = atomicAdd(&scnt[ln], 1u); if (p < SCAP) sbuf[ln][p] = (u32)(base + 0); }
    if (d1 <= tauh && base + 1 != node) { u32 p = atomicAdd(&scnt[ln], 1u); if (p < SCAP) sbuf[ln][p] = (u32)(base + 1); }
    if (d2 <= tauh && base + 2 != node) { u32 p = atomicAdd(&scnt[ln], 1u); if (p < SCAP) sbuf[ln][p] = (u32)(base + 2); }
    if (d3 <= tauh && base + 3 != node) { u32 p = atomicAdd(&scnt[ln], 1u); if (p < SCAP) sbuf[ln][p] = (u32)(base + 3); }
  }
  __syncthreads();

  const u32 cnt = scnt[ln];
  const bool fb = (bool)__any((int)(cnt > SCAP));

  if (!fb) {
    // ---- phase 2: exact top-16 over survivors ----
    float a2[16];
#pragma unroll
    for (int q = 0; q < 16; ++q) a2[q] = INF;
#pragma unroll 2
    for (int q = sub; q < SCAP; q += 4) {
      u32 j = sbuf[ln][q] & (N_NODES - 1);
      float d = dist2(cx, cy, cz, xs[j], ys[j], zs[j]);
      ins16(a2, ((u32)q < cnt) ? d : INF);
    }
    merge4(a2, tid);
    const float tau = max16(a2);   // exact d16
#pragma unroll 2
    for (int q = sub; q < SCAP; q += 4) {
      u32 j = sbuf[ln][q] & (N_NODES - 1);
      float d = dist2(cx, cy, cz, xs[j], ys[j], zs[j]);
      if ((u32)q < cnt && d <= tau) {
        u32 p = atomicAdd(&ncnt[ln], 1u); if (p < 16u) nbuf[ln][p] = j;
      }
    }
  } else {
    // ---- fallback (≈never): exact full rescan for the whole wave ----
    float a3[16];
#pragma unroll
    for (int q = 0; q < 16; ++q) a3[q] = INF;
    for (int it = 0; it < 128; ++it) {
      const int v4 = (it << 2) + sub;
      float4 xv = xs4[v4], yv = ys4[v4], zv = zs4[v4];
      const int base = v4 << 2;
      float d0 = (base + 0 == node) ? INF : dist2(cx, cy, cz, xv.x, yv.x, zv.x);
      float d1 = (base + 1 == node) ? INF : dist2(cx, cy, cz, xv.y, yv.y, zv.y);
      float d2 = (base + 2 == node) ? INF : dist2(cx, cy, cz, xv.z, yv.z, zv.z);
      float d3 = (base + 3 == node) ? INF : dist2(cx, cy, cz, xv.w, yv.w, zv.w);
      ins16(a3, d0); ins16(a3, d1); ins16(a3, d2); ins16(a3, d3);
    }
    merge4(a3, tid);
    const float tau = max16(a3);
    for (int it = 0; it < 128; ++it) {
      const int v4 = (it << 2) + sub;
      float4 xv = xs4[v4], yv = ys4[v4], zv = zs4[v4];
      const int base = v4 << 2;
      float d0 = dist2(cx, cy, cz, xv.x, yv.x, zv.x);
      float d1 = dist2(cx, cy, cz, xv.y, yv.y, zv.y);
      float d2 = dist2(cx, cy, cz, xv.z, yv.z, zv.z);
      float d3 = dist2(cx, cy, cz, xv.w, yv.w, zv.w);
      if (d0 <= tau && base + 0 != node) { u32 p = atomicAdd(&ncnt[ln], 1u); if (p < 16u) nbuf[ln][p] = (u32)(base + 0); }
      if (d1 <= tau && base + 1 != node) { u32 p = atomicAdd(&ncnt[ln], 1u); if (p < 16u) nbuf[ln][p] = (u32)(base + 1); }
      if (d2 <= tau && base + 2 != node) { u32 p = atomicAdd(&ncnt[ln], 1u); if (p < 16u) nbuf[ln][p] = (u32)(base + 2); }
      if (d3 <= tau && base + 3 != node) { u32 p = atomicAdd(&ncnt[ln], 1u); if (p < 16u) nbuf[ln][p] = (u32)(base + 3); }
    }
  }
  __syncthreads();

  const size_t gnode = ((size_t)s << 11) + node;
  uint4 nb = *(const uint4*)&nbuf[ln][sub << 2];
  *(int4*)(nbr + gnode * 16 + (sub << 2)) =
      make_int4((int)nb.x, (int)nb.y, (int)nb.z, (int)nb.w);

  // ---- layer 1: mean over {self + 16 nbrs}, 3x64 matmul + ReLU ----
  float sx, sy, sz;
  if (sub == 0) { sx = cx; sy = cy; sz = cz; } else { sx = 0.f; sy = 0.f; sz = 0.f; }
  sx += xs[nb.x] + xs[nb.y] + xs[nb.z] + xs[nb.w];
  sy += ys[nb.x] + ys[nb.y] + ys[nb.z] + ys[nb.w];
  sz += zs[nb.x] + zs[nb.y] + zs[nb.z] + zs[nb.w];
  sx += __shfl_xor(sx, 1); sx += __shfl_xor(sx, 2);
  sy += __shfl_xor(sy, 1); sy += __shfl_xor(sy, 2);
  sz += __shfl_xor(sz, 1); sz += __shfl_xor(sz, 2);
  const float inv = 1.0f / 17.0f;
  float mx = sx * inv, my = sy * inv, mz = sz * inv;

  u32 pk[8];
#pragma unroll
  for (int oo = 0; oo < 16; oo += 2) {
    const int o = (sub << 4) + oo;
    float v0 = fmaf(mz, w1s[128+o],   fmaf(my, w1s[64+o],   fmaf(mx, w1s[o],   b1s[o])));
    float v1 = fmaf(mz, w1s[128+o+1], fmaf(my, w1s[64+o+1], fmaf(mx, w1s[o+1], b1s[o+1])));
    pk[oo >> 1] = packbf(fmaxf(v0, 0.0f), fmaxf(v1, 0.0f));
  }
  uint4* xo = (uint4*)(x1 + gnode * 32 + (sub << 3));
  xo[0] = make_uint4(pk[0], pk[1], pk[2], pk[3]);
  xo[1] = make_uint4(pk[4], pk[5], pk[6], pk[7]);
}

// ---------------------------------------------------------------------------
// K2: gather-mean of x1 over {nbr,self} -> bf16 A-tile (LDS, swizzled) ->
// MFMA GEMM [128 nodes x 64] @ [64 x 128] with hi/lo-split bf16 weights ->
// ReLU -> x2 bf16. 512 blocks x 256 thr (4 waves; wave = 32 node-rows).
// ---------------------------------------------------------------------------
__global__ __launch_bounds__(256) void k2_gcn2(
    const u32* __restrict__ x1, const int* __restrict__ nbr,
    const float* __restrict__ W2, const float* __restrict__ b2,
    u32* __restrict__ x2)
{
  __shared__ uint4 AldsV[1024];   // 16 KB
  __shared__ uint4 BhiV[1024];    // 16 KB
  __shared__ uint4 BloV[1024];    // 16 KB
  char* Alds = (char*)AldsV; char* Bhi = (char*)BhiV; char* Blo = (char*)BloV;
  const int tid   = threadIdx.x;
  const int node0 = blockIdx.x << 7;

#pragma unroll
  for (int i = 0; i < 32; ++i) {
    int e = tid + (i << 8);
    int k = e >> 7, n = e & 127;
    float w = W2[e];
    u32 hb = packbf(w, 0.0f) & 0xFFFFu;
    float whi = __uint_as_float(hb << 16);
    u32 lb = packbf(w - whi, 0.0f) & 0xFFFFu;
    int byte = n * 128 + ((2 * k) ^ ((n & 7) << 4));
    *(unsigned short*)(Bhi + byte) = (unsigned short)hb;
    *(unsigned short*)(Blo + byte) = (unsigned short)lb;
  }

  {
    const int r = tid >> 1, half = tid & 1;
    const size_t gnode = (size_t)node0 + r;
    const u32* selfp = x1 + gnode * 32 + half * 16;
    const u32* x1s   = x1 + ((gnode >> 11) << 11) * 32;
    const int* nb    = nbr + gnode * 16;
    float a[32];
#pragma unroll
    for (int q = 0; q < 4; ++q) {
      uint4 v = *(const uint4*)(selfp + (q << 2));
      a[8*q+0] = bflo(v.x); a[8*q+1] = bfhi(v.x);
      a[8*q+2] = bflo(v.y); a[8*q+3] = bfhi(v.y);
      a[8*q+4] = bflo(v.z); a[8*q+5] = bfhi(v.z);
      a[8*q+6] = bflo(v.w); a[8*q+7] = bfhi(v.w);
    }
#pragma unroll
    for (int t = 0; t < 16; ++t) {
      const u32* rp = x1s + (size_t)nb[t] * 32 + half * 16;
#pragma unroll
      for (int q = 0; q < 4; ++q) {
        uint4 v = *(const uint4*)(rp + (q << 2));
        a[8*q+0] += bflo(v.x); a[8*q+1] += bfhi(v.x);
        a[8*q+2] += bflo(v.y); a[8*q+3] += bfhi(v.y);
        a[8*q+4] += bflo(v.z); a[8*q+5] += bfhi(v.z);
        a[8*q+6] += bflo(v.w); a[8*q+7] += bfhi(v.w);
      }
    }
    const float inv = 1.0f / 17.0f;
    u32 pk[16];
#pragma unroll
    for (int j = 0; j < 16; ++j)
      pk[j] = packbf(a[2*j] * inv, a[2*j+1] * inv);
#pragma unroll
    for (int q = 0; q < 4; ++q) {
      int byte = r * 128 + ((((half << 6) + (q << 4))) ^ ((r & 7) << 4));
      *(uint4*)(Alds + byte) = make_uint4(pk[4*q], pk[4*q+1], pk[4*q+2], pk[4*q+3]);
    }
  }
  __syncthreads();

  const int lane = tid & 63, wv = tid >> 6;
  const int cl = lane & 15, kg = lane >> 4;

  f32x4 acc[2][8];
#pragma unroll
  for (int rt = 0; rt < 2; ++rt)
#pragma unroll
    for (int ct = 0; ct < 8; ++ct) {
      float bv = b2[(ct << 4) + cl];
      acc[rt][ct] = (f32x4){bv, bv, bv, bv};
    }

#pragma unroll
  for (int ks = 0; ks < 2; ++ks) {
    const int kb = (ks << 6) + (kg << 4);
    bf16x8 af[2];
#pragma unroll
    for (int rt = 0; rt < 2; ++rt) {
      int row = (wv << 5) + (rt << 4) + cl;
      af[rt] = *(const bf16x8*)(Alds + row * 128 + (kb ^ ((row & 7) << 4)));
    }
#pragma unroll
    for (int ct = 0; ct < 8; ++ct) {
      int n = (ct << 4) + cl;
      int byte = n * 128 + (kb ^ ((n & 7) << 4));
      bf16x8 bh = *(const bf16x8*)(Bhi + byte);
      bf16x8 bl = *(const bf16x8*)(Blo + byte);
#pragma unroll
      for (int rt = 0; rt < 2; ++rt) {
        acc[rt][ct] = __builtin_amdgcn_mfma_f32_16x16x32_bf16(af[rt], bh, acc[rt][ct], 0, 0, 0);
        acc[rt][ct] = __builtin_amdgcn_mfma_f32_16x16x32_bf16(af[rt], bl, acc[rt][ct], 0, 0, 0);
      }
    }
  }

  unsigned short* x2h = (unsigned short*)x2;
#pragma unroll
  for (int rt = 0; rt < 2; ++rt)
#pragma unroll
    for (int ct = 0; ct < 8; ++ct) {
      int colg = (ct << 4) + cl;
      int nr0  = node0 + (wv << 5) + (rt << 4) + (kg << 2);
#pragma unroll
      for (int r = 0; r < 4; ++r) {
        float v = fmaxf(acc[rt][ct][r], 0.0f);
        x2h[(size_t)(nr0 + r) * 128 + colg] = (unsigned short)(packbf(v, 0.0f) & 0xFFFFu);
      }
    }
}

// ---------------------------------------------------------------------------
// K3: final linear 128->128 via MFMA, hi/lo-split weights, f32 out.
// ---------------------------------------------------------------------------
__global__ __launch_bounds__(256) void k3_final(
    const u32* __restrict__ x2, const float* __restrict__ Wf,
    const float* __restrict__ bfv, float* __restrict__ out)
{
  __shared__ uint4 AldsV[2048];   // 32 KB
  __shared__ uint4 BhiV[1024];    // 16 KB
  __shared__ uint4 BloV[1024];
  char* Alds = (char*)AldsV; char* Bhi = (char*)BhiV; char* Blo = (char*)BloV;
  const int tid   = threadIdx.x;
  const int node0 = (blockIdx.x >> 1) << 7;
  const int ch0   = (blockIdx.x & 1) << 6;

#pragma unroll
  for (int i = 0; i < 32; ++i) {
    int e = tid + (i << 8);
    int k = e >> 6, n = e & 63;
    float w = Wf[k * 128 + ch0 + n];
    u32 hb = packbf(w, 0.0f) & 0xFFFFu;
    float whi = __uint_as_float(hb << 16);
    u32 lb = packbf(w - whi, 0.0f) & 0xFFFFu;
    int byte = n * 256 + ((2 * k) ^ ((n & 15) << 4));
    *(unsigned short*)(Bhi + byte) = (unsigned short)hb;
    *(unsigned short*)(Blo + byte) = (unsigned short)lb;
  }

  {
    const int r = tid >> 1, half = tid & 1;
    const u32* src = x2 + (size_t)(node0 + r) * 64 + half * 32;
#pragma unroll
    for (int q = 0; q < 8; ++q) {
      uint4 v = *(const uint4*)(src + (q << 2));
      int byte = r * 256 + ((((half << 7) + (q << 4))) ^ ((r & 15) << 4));
      *(uint4*)(Alds + byte) = v;
    }
  }
  __syncthreads();

  const int lane = tid & 63, wv = tid >> 6;
  const int cl = lane & 15, kg = lane >> 4;

  f32x4 acc[2][4];
#pragma unroll
  for (int rt = 0; rt < 2; ++rt)
#pragma unroll
    for (int ct = 0; ct < 4; ++ct) {
      float bv = bfv[ch0 + (ct << 4) + cl];
      acc[rt][ct] = (f32x4){bv, bv, bv, bv};
    }

#pragma unroll
  for (int ks = 0; ks < 4; ++ks) {
    const int kb = (ks << 6) + (kg << 4);
    bf16x8 af[2];
#pragma unroll
    for (int rt = 0; rt < 2; ++rt) {
      int row = (wv << 5) + (rt << 4) + cl;
      af[rt] = *(const bf16x8*)(Alds + row * 256 + (kb ^ ((row & 15) << 4)));
    }
#pragma unroll
    for (int ct = 0; ct < 4; ++ct) {
      int n = (ct << 4) + cl;
      int byte = n * 256 + (kb ^ ((n & 15) << 4));
      bf16x8 bh = *(const bf16x8*)(Bhi + byte);
      bf16x8 bl = *(const bf16x8*)(Blo + byte);
#pragma unroll
      for (int rt = 0; rt < 2; ++rt) {
        acc[rt][ct] = __builtin_amdgcn_mfma_f32_16x16x32_bf16(af[rt], bh, acc[rt][ct], 0, 0, 0);
        acc[rt][ct] = __builtin_amdgcn_mfma_f32_16x16x32_bf16(af[rt], bl, acc[rt][ct], 0, 0, 0);
      }
    }
  }

#pragma unroll
  for (int rt = 0; rt < 2; ++rt)
#pragma unroll
    for (int ct = 0; ct < 4; ++ct) {
      int col = ch0 + (ct << 4) + cl;
      int nr0 = node0 + (wv << 5) + (rt << 4) + (kg << 2);
#pragma unroll
      for (int r = 0; r < 4; ++r)
        out[(size_t)(nr0 + r) * 128 + col] = acc[rt][ct][r];
    }
}

extern "C" void kernel_launch(void* const* d_in, const int* in_sizes, int n_in,
                              void* d_out, int out_size, void* d_ws, size_t ws_size,
                              hipStream_t stream) {
  const float* coords = (const float*)d_in[0];
  const float* W1 = (const float*)d_in[1];
  const float* b1 = (const float*)d_in[2];
  const float* W2 = (const float*)d_in[3];
  const float* b2 = (const float*)d_in[4];
  const float* Wf = (const float*)d_in[5];
  const float* bf = (const float*)d_in[6];
  float* out = (float*)d_out;

  char* ws = (char*)d_ws;
  int* nbr = (int*)ws;                                  //  4 MB: [32,2048,16] i32
  u32* x1  = (u32*)(ws + (size_t)4  * 1024 * 1024);     //  8 MB: [32,2048,64] bf16
  u32* x2  = (u32*)(ws + (size_t)12 * 1024 * 1024);     // 16 MB: [65536,128] bf16

  k1_knn_l1<<<1024, 256, 0, stream>>>(coords, W1, b1, nbr, x1);
  k2_gcn2  <<< 512, 256, 0, stream>>>(x1, nbr, W2, b2, x2);
  k3_final <<<1024, 256, 0, stream>>>(x2, Wf, bf, out);
}

// Round 7
// 208.587 us; speedup vs baseline: 1.5242x; 1.5242x over previous
//
#include <hip/hip_runtime.h>
#include <hip/hip_bf16.h>

typedef unsigned int u32;
typedef __attribute__((ext_vector_type(8))) short bf16x8;
typedef __attribute__((ext_vector_type(4))) float f32x4;

#define N_NODES 2048
#define INF __builtin_inff()

__device__ __forceinline__ float bflo(u32 u){ return __uint_as_float(u << 16); }
__device__ __forceinline__ float bfhi(u32 u){ return __uint_as_float(u & 0xFFFF0000u); }
__device__ __forceinline__ u32 packbf(float a, float b){
  u32 ua = __float_as_uint(a), ub = __float_as_uint(b);
  u32 ra = (ua + 0x7FFFu + ((ua >> 16) & 1u)) >> 16;
  u32 rb = (ub + 0x7FFFu + ((ub >> 16) & 1u)) >> 16;
  return ra | (rb << 16);
}

__device__ __forceinline__ float dist2(float cx, float cy, float cz,
                                       float jx, float jy, float jz) {
  float dx = cx - jx, dy = cy - jy, dz = cz - jz;
  return fmaf(dz, dz, fmaf(dy, dy, dx * dx));
}

// TRUNCATED key: d^2 bits with low 11 bits replaced by index. Monotone
// non-decreasing in d; exactness certified post-merge (see boundary check).
__device__ __forceinline__ float mkkey(float d, int j, int node) {
  u32 kb = (__float_as_uint(d) & 0xFFFFF800u) | (u32)j;
  if (j == node) kb = 0x7E000000u;   // self sentinel, above all real keys
  return __uint_as_float(kb);
}

__device__ __forceinline__ void ins12(float (&ad)[12], float v) {
#pragma unroll
  for (int t = 11; t >= 1; --t)
    ad[t] = __builtin_amdgcn_fmed3f(v, ad[t-1], ad[t]);
  ad[0] = fminf(ad[0], v);
}
__device__ __forceinline__ void ins16(float (&ad)[16], float v) {
#pragma unroll
  for (int t = 15; t >= 1; --t)
    ad[t] = __builtin_amdgcn_fmed3f(v, ad[t-1], ad[t]);
  ad[0] = fminf(ad[0], v);
}

// merge 4 sorted-ascending 16-lists across sublanes (tid^1 then tid^2);
// fully sorted result, identical in all 4 sublanes.
__device__ __forceinline__ void merge4s(float (&ad)[16], int tid) {
#define CED(I, J) { float lo_ = fminf(ad[I], ad[J]); ad[J] = fmaxf(ad[I], ad[J]); ad[I] = lo_; }
#define CLEAN16 \
  CED(0,8) CED(1,9) CED(2,10) CED(3,11) CED(4,12) CED(5,13) CED(6,14) CED(7,15) \
  CED(0,4) CED(1,5) CED(2,6)  CED(3,7)  CED(8,12) CED(9,13) CED(10,14) CED(11,15) \
  CED(0,2) CED(1,3) CED(4,6)  CED(5,7)  CED(8,10) CED(9,11) CED(12,14) CED(13,15) \
  CED(0,1) CED(2,3) CED(4,5)  CED(6,7)  CED(8,9)  CED(10,11) CED(12,13) CED(14,15)
  float bd[16];
#pragma unroll
  for (int q = 0; q < 16; ++q) bd[q] = __shfl(ad[q], tid ^ 1);
#pragma unroll
  for (int q = 0; q < 16; ++q) ad[q] = fminf(ad[q], bd[15 - q]);
  CLEAN16
#pragma unroll
  for (int q = 0; q < 16; ++q) bd[q] = __shfl(ad[q], tid ^ 2);
#pragma unroll
  for (int q = 0; q < 16; ++q) ad[q] = fminf(ad[q], bd[15 - q]);
  CLEAN16
#undef CLEAN16
#undef CED
}

// ---------------------------------------------------------------------------
// K1: exact KNN (K=16, self-excluded) + GCN layer 1 (3->64) fused.
// Single truncated-key scan (depth 12/lane, 4 lanes/node) + exactness
// certificate (depth check + boundary gap check) + rare exact fallback.
// ---------------------------------------------------------------------------
__global__ __launch_bounds__(256) void k1_knn_l1(
    const float* __restrict__ coords, const float* __restrict__ W1,
    const float* __restrict__ b1, int* __restrict__ nbr, u32* __restrict__ x1)
{
  __shared__ float xs[N_NODES], ys[N_NODES], zs[N_NODES];  // 24 KB SoA
  __shared__ u32   nbuf[64][16];                           // fallback only
  __shared__ u32   ncnt[64];
  __shared__ float w1s[192];
  __shared__ float b1s[64];
  const int tid   = threadIdx.x;
  const int s     = blockIdx.x >> 5;
  const int chunk = blockIdx.x & 31;
  const float* cs = coords + (size_t)s * (N_NODES * 3);
  for (int k = tid; k < N_NODES; k += 256) {
    xs[k] = cs[3*k]; ys[k] = cs[3*k+1]; zs[k] = cs[3*k+2];
  }
  if (tid < 192) w1s[tid] = W1[tid];
  if (tid < 64)  b1s[tid] = b1[tid];
  __syncthreads();

  const int node = (chunk << 6) + (tid >> 2);
  const int sub  = tid & 3;
  const int ln   = tid >> 2;
  const float cx = xs[node], cy = ys[node], cz = zs[node];

  const float4* xs4 = (const float4*)xs;
  const float4* ys4 = (const float4*)ys;
  const float4* zs4 = (const float4*)zs;

  // ---- single scan: 64 iters x 8 candidates, 12-deep truncated-key list ----
  float ad[12];
#pragma unroll
  for (int q = 0; q < 12; ++q) ad[q] = INF;

  for (int it = 0; it < 64; ++it) {
    const int v4a = (it << 3) + sub, v4b = v4a + 4;
    float4 xa = xs4[v4a], ya = ys4[v4a], za = zs4[v4a];
    float4 xb = xs4[v4b], yb = ys4[v4b], zb = zs4[v4b];
    const int ba = v4a << 2, bb = v4b << 2;
    ins12(ad, mkkey(dist2(cx,cy,cz, xa.x,ya.x,za.x), ba+0, node));
    ins12(ad, mkkey(dist2(cx,cy,cz, xa.y,ya.y,za.y), ba+1, node));
    ins12(ad, mkkey(dist2(cx,cy,cz, xa.z,ya.z,za.z), ba+2, node));
    ins12(ad, mkkey(dist2(cx,cy,cz, xa.w,ya.w,za.w), ba+3, node));
    ins12(ad, mkkey(dist2(cx,cy,cz, xb.x,yb.x,zb.x), bb+0, node));
    ins12(ad, mkkey(dist2(cx,cy,cz, xb.y,yb.y,zb.y), bb+1, node));
    ins12(ad, mkkey(dist2(cx,cy,cz, xb.z,yb.z,zb.z), bb+2, node));
    ins12(ad, mkkey(dist2(cx,cy,cz, xb.w,yb.w,zb.w), bb+3, node));
  }

  const float myMax = ad[11];          // every dropped key > myMax (final)
  float md[16];
#pragma unroll
  for (int q = 0; q < 12; ++q) md[q] = ad[q];
  md[12] = md[13] = md[14] = md[15] = __uint_as_float(0x7F000000u);
  merge4s(md, tid);                    // sorted; md[15] = 16th smallest kept

  // ---- certificate ----
  const float md15 = md[15];
  float mnext = INF;                   // smallest own-kept key > md15
#pragma unroll
  for (int q = 11; q >= 0; --q) mnext = (ad[q] > md15) ? ad[q] : mnext;
  float cand17 = fminf(mnext, __shfl(mnext, tid ^ 1));
  cand17 = fminf(cand17, __shfl(cand17, tid ^ 2));   // 17th smallest (if depth ok)

  const u32 t15 = __float_as_uint(md15)   & 0xFFFFF800u;
  const u32 t17 = __float_as_uint(cand17) & 0xFFFFF800u;
  const bool ok = (myMax >= cand17) & (t17 >= t15 + 0x800u);

  int j0, j1, j2, j3;
  if (__all((int)ok)) {
    j0 = (int)(__float_as_uint(md[(sub<<2)+0]) & 0x7FFu);
    j1 = (int)(__float_as_uint(md[(sub<<2)+1]) & 0x7FFu);
    j2 = (int)(__float_as_uint(md[(sub<<2)+2]) & 0x7FFu);
    j3 = (int)(__float_as_uint(md[(sub<<2)+3]) & 0x7FFu);
  } else {
    // ---- exact fallback (≈1 node/launch): two-scan exact distances ----
    float a3[16];
#pragma unroll
    for (int q = 0; q < 16; ++q) a3[q] = INF;
#pragma unroll 1
    for (int it = 0; it < 128; ++it) {
      const int v4 = (it << 2) + sub;
      float4 xv = xs4[v4], yv = ys4[v4], zv = zs4[v4];
      const int base = v4 << 2;
      float d0 = (base + 0 == node) ? INF : dist2(cx,cy,cz, xv.x,yv.x,zv.x);
      float d1 = (base + 1 == node) ? INF : dist2(cx,cy,cz, xv.y,yv.y,zv.y);
      float d2 = (base + 2 == node) ? INF : dist2(cx,cy,cz, xv.z,yv.z,zv.z);
      float d3 = (base + 3 == node) ? INF : dist2(cx,cy,cz, xv.w,yv.w,zv.w);
      ins16(a3, d0); ins16(a3, d1); ins16(a3, d2); ins16(a3, d3);
    }
    merge4s(a3, tid);
    const float tau = a3[15];          // exact 16th-smallest distance
    if (sub == 0) ncnt[ln] = 0;
    asm volatile("s_waitcnt lgkmcnt(0)" ::: "memory");
#pragma unroll 1
    for (int it = 0; it < 128; ++it) {
      const int v4 = (it << 2) + sub;
      float4 xv = xs4[v4], yv = ys4[v4], zv = zs4[v4];
      const int base = v4 << 2;
      float d0 = dist2(cx,cy,cz, xv.x,yv.x,zv.x);
      float d1 = dist2(cx,cy,cz, xv.y,yv.y,zv.y);
      float d2 = dist2(cx,cy,cz, xv.z,yv.z,zv.z);
      float d3 = dist2(cx,cy,cz, xv.w,yv.w,zv.w);
      if (d0 <= tau && base + 0 != node) { u32 p = atomicAdd(&ncnt[ln], 1u); if (p < 16u) nbuf[ln][p] = (u32)(base + 0); }
      if (d1 <= tau && base + 1 != node) { u32 p = atomicAdd(&ncnt[ln], 1u); if (p < 16u) nbuf[ln][p] = (u32)(base + 1); }
      if (d2 <= tau && base + 2 != node) { u32 p = atomicAdd(&ncnt[ln], 1u); if (p < 16u) nbuf[ln][p] = (u32)(base + 2); }
      if (d3 <= tau && base + 3 != node) { u32 p = atomicAdd(&ncnt[ln], 1u); if (p < 16u) nbuf[ln][p] = (u32)(base + 3); }
    }
    asm volatile("s_waitcnt lgkmcnt(0)" ::: "memory");
    uint4 nb4 = *(const uint4*)&nbuf[ln][sub << 2];
    j0 = (int)nb4.x; j1 = (int)nb4.y; j2 = (int)nb4.z; j3 = (int)nb4.w;
  }

  const size_t gnode = ((size_t)s << 11) + node;
  *(int4*)(nbr + gnode * 16 + (sub << 2)) = make_int4(j0, j1, j2, j3);

  // ---- layer 1: mean over {self + 16 nbrs}, 3x64 matmul + ReLU ----
  float sx, sy, sz;
  if (sub == 0) { sx = cx; sy = cy; sz = cz; } else { sx = 0.f; sy = 0.f; sz = 0.f; }
  sx += xs[j0] + xs[j1] + xs[j2] + xs[j3];
  sy += ys[j0] + ys[j1] + ys[j2] + ys[j3];
  sz += zs[j0] + zs[j1] + zs[j2] + zs[j3];
  sx += __shfl_xor(sx, 1); sx += __shfl_xor(sx, 2);
  sy += __shfl_xor(sy, 1); sy += __shfl_xor(sy, 2);
  sz += __shfl_xor(sz, 1); sz += __shfl_xor(sz, 2);
  const float inv = 1.0f / 17.0f;
  float mx = sx * inv, my = sy * inv, mz = sz * inv;

  u32 pk[8];
#pragma unroll
  for (int oo = 0; oo < 16; oo += 2) {
    const int o = (sub << 4) + oo;
    float v0 = fmaf(mz, w1s[128+o],   fmaf(my, w1s[64+o],   fmaf(mx, w1s[o],   b1s[o])));
    float v1 = fmaf(mz, w1s[128+o+1], fmaf(my, w1s[64+o+1], fmaf(mx, w1s[o+1], b1s[o+1])));
    pk[oo >> 1] = packbf(fmaxf(v0, 0.0f), fmaxf(v1, 0.0f));
  }
  uint4* xo = (uint4*)(x1 + gnode * 32 + (sub << 3));
  xo[0] = make_uint4(pk[0], pk[1], pk[2], pk[3]);
  xo[1] = make_uint4(pk[4], pk[5], pk[6], pk[7]);
}

// ---------------------------------------------------------------------------
// K2: gather-mean of x1 over {nbr,self} -> bf16 A-tile (LDS, swizzled) ->
// MFMA GEMM [128 x 64] @ [64 x 128], hi/lo-split bf16 weights -> ReLU -> x2.
// ---------------------------------------------------------------------------
__global__ __launch_bounds__(256) void k2_gcn2(
    const u32* __restrict__ x1, const int* __restrict__ nbr,
    const float* __restrict__ W2, const float* __restrict__ b2,
    u32* __restrict__ x2)
{
  __shared__ uint4 AldsV[1024];   // 16 KB
  __shared__ uint4 BhiV[1024];    // 16 KB
  __shared__ uint4 BloV[1024];    // 16 KB
  char* Alds = (char*)AldsV; char* Bhi = (char*)BhiV; char* Blo = (char*)BloV;
  const int tid   = threadIdx.x;
  const int node0 = blockIdx.x << 7;

#pragma unroll
  for (int i = 0; i < 32; ++i) {
    int e = tid + (i << 8);
    int k = e >> 7, n = e & 127;
    float w = W2[e];
    u32 hb = packbf(w, 0.0f) & 0xFFFFu;
    float whi = __uint_as_float(hb << 16);
    u32 lb = packbf(w - whi, 0.0f) & 0xFFFFu;
    int byte = n * 128 + ((2 * k) ^ ((n & 7) << 4));
    *(unsigned short*)(Bhi + byte) = (unsigned short)hb;
    *(unsigned short*)(Blo + byte) = (unsigned short)lb;
  }

  {
    const int r = tid >> 1, half = tid & 1;
    const size_t gnode = (size_t)node0 + r;
    const u32* selfp = x1 + gnode * 32 + half * 16;
    const u32* x1s   = x1 + ((gnode >> 11) << 11) * 32;
    const int* nb    = nbr + gnode * 16;
    float a[32];
#pragma unroll
    for (int q = 0; q < 4; ++q) {
      uint4 v = *(const uint4*)(selfp + (q << 2));
      a[8*q+0] = bflo(v.x); a[8*q+1] = bfhi(v.x);
      a[8*q+2] = bflo(v.y); a[8*q+3] = bfhi(v.y);
      a[8*q+4] = bflo(v.z); a[8*q+5] = bfhi(v.z);
      a[8*q+6] = bflo(v.w); a[8*q+7] = bfhi(v.w);
    }
#pragma unroll
    for (int t = 0; t < 16; ++t) {
      const u32* rp = x1s + (size_t)nb[t] * 32 + half * 16;
#pragma unroll
      for (int q = 0; q < 4; ++q) {
        uint4 v = *(const uint4*)(rp + (q << 2));
        a[8*q+0] += bflo(v.x); a[8*q+1] += bfhi(v.x);
        a[8*q+2] += bflo(v.y); a[8*q+3] += bfhi(v.y);
        a[8*q+4] += bflo(v.z); a[8*q+5] += bfhi(v.z);
        a[8*q+6] += bflo(v.w); a[8*q+7] += bfhi(v.w);
      }
    }
    const float inv = 1.0f / 17.0f;
    u32 pk[16];
#pragma unroll
    for (int j = 0; j < 16; ++j)
      pk[j] = packbf(a[2*j] * inv, a[2*j+1] * inv);
#pragma unroll
    for (int q = 0; q < 4; ++q) {
      int byte = r * 128 + ((((half << 6) + (q << 4))) ^ ((r & 7) << 4));
      *(uint4*)(Alds + byte) = make_uint4(pk[4*q], pk[4*q+1], pk[4*q+2], pk[4*q+3]);
    }
  }
  __syncthreads();

  const int lane = tid & 63, wv = tid >> 6;
  const int cl = lane & 15, kg = lane >> 4;

  f32x4 acc[2][8];
#pragma unroll
  for (int rt = 0; rt < 2; ++rt)
#pragma unroll
    for (int ct = 0; ct < 8; ++ct) {
      float bv = b2[(ct << 4) + cl];
      acc[rt][ct] = (f32x4){bv, bv, bv, bv};
    }

#pragma unroll
  for (int ks = 0; ks < 2; ++ks) {
    const int kb = (ks << 6) + (kg << 4);
    bf16x8 af[2];
#pragma unroll
    for (int rt = 0; rt < 2; ++rt) {
      int row = (wv << 5) + (rt << 4) + cl;
      af[rt] = *(const bf16x8*)(Alds + row * 128 + (kb ^ ((row & 7) << 4)));
    }
#pragma unroll
    for (int ct = 0; ct < 8; ++ct) {
      int n = (ct << 4) + cl;
      int byte = n * 128 + (kb ^ ((n & 7) << 4));
      bf16x8 bh = *(const bf16x8*)(Bhi + byte);
      bf16x8 bl = *(const bf16x8*)(Blo + byte);
#pragma unroll
      for (int rt = 0; rt < 2; ++rt) {
        acc[rt][ct] = __builtin_amdgcn_mfma_f32_16x16x32_bf16(af[rt], bh, acc[rt][ct], 0, 0, 0);
        acc[rt][ct] = __builtin_amdgcn_mfma_f32_16x16x32_bf16(af[rt], bl, acc[rt][ct], 0, 0, 0);
      }
    }
  }

  unsigned short* x2h = (unsigned short*)x2;
#pragma unroll
  for (int rt = 0; rt < 2; ++rt)
#pragma unroll
    for (int ct = 0; ct < 8; ++ct) {
      int colg = (ct << 4) + cl;
      int nr0  = node0 + (wv << 5) + (rt << 4) + (kg << 2);
#pragma unroll
      for (int r = 0; r < 4; ++r) {
        float v = fmaxf(acc[rt][ct][r], 0.0f);
        x2h[(size_t)(nr0 + r) * 128 + colg] = (unsigned short)(packbf(v, 0.0f) & 0xFFFFu);
      }
    }
}

// ---------------------------------------------------------------------------
// K3: final linear 128->128 via MFMA, hi/lo-split weights, f32 out.
// ---------------------------------------------------------------------------
__global__ __launch_bounds__(256) void k3_final(
    const u32* __restrict__ x2, const float* __restrict__ Wf,
    const float* __restrict__ bfv, float* __restrict__ out)
{
  __shared__ uint4 AldsV[2048];   // 32 KB
  __shared__ uint4 BhiV[1024];    // 16 KB
  __shared__ uint4 BloV[1024];
  char* Alds = (char*)AldsV; char* Bhi = (char*)BhiV; char* Blo = (char*)BloV;
  const int tid   = threadIdx.x;
  const int node0 = (blockIdx.x >> 1) << 7;
  const int ch0   = (blockIdx.x & 1) << 6;

#pragma unroll
  for (int i = 0; i < 32; ++i) {
    int e = tid + (i << 8);
    int k = e >> 6, n = e & 63;
    float w = Wf[k * 128 + ch0 + n];
    u32 hb = packbf(w, 0.0f) & 0xFFFFu;
    float whi = __uint_as_float(hb << 16);
    u32 lb = packbf(w - whi, 0.0f) & 0xFFFFu;
    int byte = n * 256 + ((2 * k) ^ ((n & 15) << 4));
    *(unsigned short*)(Bhi + byte) = (unsigned short)hb;
    *(unsigned short*)(Blo + byte) = (unsigned short)lb;
  }

  {
    const int r = tid >> 1, half = tid & 1;
    const u32* src = x2 + (size_t)(node0 + r) * 64 + half * 32;
#pragma unroll
    for (int q = 0; q < 8; ++q) {
      uint4 v = *(const uint4*)(src + (q << 2));
      int byte = r * 256 + ((((half << 7) + (q << 4))) ^ ((r & 15) << 4));
      *(uint4*)(Alds + byte) = v;
    }
  }
  __syncthreads();

  const int lane = tid & 63, wv = tid >> 6;
  const int cl = lane & 15, kg = lane >> 4;

  f32x4 acc[2][4];
#pragma unroll
  for (int rt = 0; rt < 2; ++rt)
#pragma unroll
    for (int ct = 0; ct < 4; ++ct) {
      float bv = bfv[ch0 + (ct << 4) + cl];
      acc[rt][ct] = (f32x4){bv, bv, bv, bv};
    }

#pragma unroll
  for (int ks = 0; ks < 4; ++ks) {
    const int kb = (ks << 6) + (kg << 4);
    bf16x8 af[2];
#pragma unroll
    for (int rt = 0; rt < 2; ++rt) {
      int row = (wv << 5) + (rt << 4) + cl;
      af[rt] = *(const bf16x8*)(Alds + row * 256 + (kb ^ ((row & 15) << 4)));
    }
#pragma unroll
    for (int ct = 0; ct < 4; ++ct) {
      int n = (ct << 4) + cl;
      int byte = n * 256 + (kb ^ ((n & 15) << 4));
      bf16x8 bh = *(const bf16x8*)(Bhi + byte);
      bf16x8 bl = *(const bf16x8*)(Blo + byte);
#pragma unroll
      for (int rt = 0; rt < 2; ++rt) {
        acc[rt][ct] = __builtin_amdgcn_mfma_f32_16x16x32_bf16(af[rt], bh, acc[rt][ct], 0, 0, 0);
        acc[rt][ct] = __builtin_amdgcn_mfma_f32_16x16x32_bf16(af[rt], bl, acc[rt][ct], 0, 0, 0);
      }
    }
  }

#pragma unroll
  for (int rt = 0; rt < 2; ++rt)
#pragma unroll
    for (int ct = 0; ct < 4; ++ct) {
      int col = ch0 + (ct << 4) + cl;
      int nr0 = node0 + (wv << 5) + (rt << 4) + (kg << 2);
#pragma unroll
      for (int r = 0; r < 4; ++r)
        out[(size_t)(nr0 + r) * 128 + col] = acc[rt][ct][r];
    }
}

extern "C" void kernel_launch(void* const* d_in, const int* in_sizes, int n_in,
                              void* d_out, int out_size, void* d_ws, size_t ws_size,
                              hipStream_t stream) {
  const float* coords = (const float*)d_in[0];
  const float* W1 = (const float*)d_in[1];
  const float* b1 = (const float*)d_in[2];
  const float* W2 = (const float*)d_in[3];
  const float* b2 = (const float*)d_in[4];
  const float* Wf = (const float*)d_in[5];
  const float* bf = (const float*)d_in[6];
  float* out = (float*)d_out;

  char* ws = (char*)d_ws;
  int* nbr = (int*)ws;                                  //  4 MB: [32,2048,16] i32
  u32* x1  = (u32*)(ws + (size_t)4  * 1024 * 1024);     //  8 MB: [32,2048,64] bf16
  u32* x2  = (u32*)(ws + (size_t)12 * 1024 * 1024);     // 16 MB: [65536,128] bf16

  k1_knn_l1<<<1024, 256, 0, stream>>>(coords, W1, b1, nbr, x1);
  k2_gcn2  <<< 512, 256, 0, stream>>>(x1, nbr, W2, b2, x2);
  k3_final <<<1024, 256, 0, stream>>>(x2, Wf, bf, out);
}